// Round 1
// 710.658 us; speedup vs baseline: 1.0047x; 1.0047x over previous
//
#include <hip/hip_runtime.h>

typedef __attribute__((ext_vector_type(8))) short short8;   // 8 bf16 (MFMA A/B frag)
typedef __attribute__((ext_vector_type(4))) float f32x4;    // MFMA C/D frag

#define MFMA16(a, b, c) __builtin_amdgcn_mfma_f32_16x16x32_bf16((a), (b), (c), 0, 0, 0)

// fp32 -> bf16 RNE
static __device__ inline short f2bf(float x) {
    union { float f; unsigned u; } v;
    v.f = x;
    unsigned r = v.u + 0x7fffu + ((v.u >> 16) & 1u);
    return (short)(r >> 16);
}
static __device__ inline short4 f2bf4(float4 v) {
    short4 s;
    s.x = f2bf(v.x); s.y = f2bf(v.y); s.z = f2bf(v.z); s.w = f2bf(v.w);
    return s;
}

// B=512, E=4, N=256, F=64
// out[b,n,g] = sum_e adj[b,e] @ (node[b] @ W_e + b_e) + node[b] @ W_add + b_add
//
// M-slab streaming design: the block walks adj[b] (1 MB) in 16 contiguous
// 64 KB slabs (slab p = e*4+mt covers adj rows mt*64..mt*64+63, ALL 256 k).
// Each slab's 16 float4/thread are issued into registers one phase early
// (T14 async-stage split) so HBM loads stay in flight across the barriers.
// MFMA k-dim runs the full 256 against a full-height hiddenT per e.
__global__ __launch_bounds__(256, 2) void gconv_kernel(
    const float* __restrict__ node,    // [512,256,64]
    const float* __restrict__ adj,     // [512,4,256,256]
    const float* __restrict__ W_edge,  // [4,64,64]
    const float* __restrict__ b_edge,  // [4,64]
    const float* __restrict__ W_add,   // [64,64]
    const float* __restrict__ b_add,   // [64]
    float* __restrict__ out)           // [512,256,64]
{
    // row strides 264/72 shorts = 132/36 dwords (== 4 mod 32): 16-lane frag
    // reads land 8 lanes per bank-quad = balanced (ds_read_b128 floor).
    __shared__ short adjL[64][264];      // adj slab [m_local][k] bf16  33792 B
    __shared__ short hiddenT[64][264];   // hidden_e^T [g][m]           33792 B
    __shared__ short wT[64][72];         // weight^T [g][f]              9216 B
                                         // total 76800 B -> 2 blocks/CU
    const int b    = blockIdx.x;
    const int t    = threadIdx.x;
    const int lane = t & 63;
    const int w    = t >> 6;        // wave 0..3
    const int col  = lane & 15;     // A-row / B-col / D-col within 16-tile
    const int kq   = lane >> 4;     // k-offset 8*kq; D-rows 4*kq..4*kq+3

    const float* nodeB = node + (size_t)b * (256 * 64);
    const float* adjB  = adj  + (size_t)b * (4 * 256 * 256);

    // ---- node[b] A-fragments -> registers (rows st*64+16w+col) ----
    short8 anode[4][2];
    #pragma unroll
    for (int st = 0; st < 4; ++st)
        #pragma unroll
        for (int h = 0; h < 2; ++h) {
            const float* p = nodeB + (st * 64 + 16 * w + col) * 64 + 32 * h + 8 * kq;
            float4 v0 = *(const float4*)p;
            float4 v1 = *(const float4*)(p + 4);
            short8 a;
            a[0] = f2bf(v0.x); a[1] = f2bf(v0.y); a[2] = f2bf(v0.z); a[3] = f2bf(v0.w);
            a[4] = f2bf(v1.x); a[5] = f2bf(v1.y); a[6] = f2bf(v1.z); a[7] = f2bf(v1.w);
            anode[st][h] = a;
        }

    // ---- staging registers: issue slab p=0 (contiguous 64 KB) ----
    // v[i] = adj_slab[row = 4i + w][cols 4*lane .. 4*lane+3]
    float4 v[16];
    {
        const float* s0 = adjB + t * 4;
        #pragma unroll
        for (int i = 0; i < 16; ++i)
            v[i] = *(const float4*)(s0 + i * 1024);
    }

    // ---- stage W_add^T -> wT ----
    #pragma unroll
    for (int i = 0; i < 16; ++i) {
        int idx = i * 256 + t;
        wT[idx & 63][idx >> 6] = f2bf(W_add[idx]);
    }
    __syncthreads();

    // ---- residual: acc[st][ct] = node_rows(st) @ W_add ----
    f32x4 acc[4][4];
    {
        const f32x4 zf = {0.f, 0.f, 0.f, 0.f};
        #pragma unroll
        for (int st = 0; st < 4; ++st)
            #pragma unroll
            for (int ct = 0; ct < 4; ++ct)
                acc[st][ct] = zf;
        #pragma unroll
        for (int h = 0; h < 2; ++h) {
            short8 bfr[4];
            #pragma unroll
            for (int ct = 0; ct < 4; ++ct)
                bfr[ct] = *(const short8*)&wT[16 * ct + col][32 * h + 8 * kq];
            #pragma unroll
            for (int st = 0; st < 4; ++st)
                #pragma unroll
                for (int ct = 0; ct < 4; ++ct)
                    acc[st][ct] = MFMA16(anode[st][h], bfr[ct], acc[st][ct]);
        }
    }
    __syncthreads();    // wT reads done before e-loop restage

    for (int e = 0; e < 4; ++e) {
        // ---- stage W_edge[e]^T -> wT ----
        const float* We = W_edge + e * (64 * 64);
        #pragma unroll
        for (int i = 0; i < 16; ++i) {
            int idx = i * 256 + t;
            wT[idx & 63][idx >> 6] = f2bf(We[idx]);
        }
        float bedge[4];
        #pragma unroll
        for (int ct = 0; ct < 4; ++ct)
            bedge[ct] = b_edge[e * 64 + 16 * ct + col];
        __syncthreads();

        // ---- hidden_e = node @ W_e + b_e  -> hiddenT[g][m] bf16 (all 256 m) ----
        #pragma unroll
        for (int ct = 0; ct < 4; ++ct) {
            short8 b0 = *(const short8*)&wT[16 * ct + col][8 * kq];
            short8 b1 = *(const short8*)&wT[16 * ct + col][32 + 8 * kq];
            #pragma unroll
            for (int st = 0; st < 4; ++st) {
                f32x4 h = {0.f, 0.f, 0.f, 0.f};
                h = MFMA16(anode[st][0], b0, h);
                h = MFMA16(anode[st][1], b1, h);
                short4 s;
                s.x = f2bf(h[0] + bedge[ct]); s.y = f2bf(h[1] + bedge[ct]);
                s.z = f2bf(h[2] + bedge[ct]); s.w = f2bf(h[3] + bedge[ct]);
                *(short4*)&hiddenT[16 * ct + col][st * 64 + 16 * w + 4 * kq] = s;
            }
        }
        __syncthreads();

        // ---- acc[mt][·] += adj rows (mt*64..+63) @ hidden_e, K=256 ----
        #pragma unroll
        for (int mt = 0; mt < 4; ++mt) {
            // convert staged regs (slab p = e*4+mt) -> adjL
            #pragma unroll
            for (int i = 0; i < 16; ++i)
                *(short4*)&adjL[4 * i + w][4 * lane] = f2bf4(v[i]);

            // issue next slab's loads; they stay in flight across the
            // barrier + MFMA phase (register-destined, no vmcnt drain)
            int p = e * 4 + mt;
            if (p < 15) {
                const float* s0 = adjB + (size_t)(p + 1) * 16384 + t * 4;
                #pragma unroll
                for (int i = 0; i < 16; ++i)
                    v[i] = *(const float4*)(s0 + i * 1024);
            }
            __syncthreads();

            #pragma unroll
            for (int ks = 0; ks < 8; ++ks) {
                short8 af = *(const short8*)&adjL[16 * w + col][32 * ks + 8 * kq];
                #pragma unroll
                for (int ct = 0; ct < 4; ++ct) {
                    short8 bf = *(const short8*)&hiddenT[16 * ct + col][32 * ks + 8 * kq];
                    acc[mt][ct] = MFMA16(af, bf, acc[mt][ct]);
                }
            }
            __syncthreads();    // adjL consumed before next slab's writes
        }
    }

    // ---- epilogue: out = acc + b_add ----
    float* outB = out + (size_t)b * (256 * 64);
    #pragma unroll
    for (int ct = 0; ct < 4; ++ct) {
        float bias = b_add[16 * ct + col];
        #pragma unroll
        for (int st = 0; st < 4; ++st) {
            int row = st * 64 + 16 * w + 4 * kq;
            #pragma unroll
            for (int r = 0; r < 4; ++r)
                outB[(size_t)(row + r) * 64 + 16 * ct + col] = acc[st][ct][r] + bias;
        }
    }
}

extern "C" void kernel_launch(void* const* d_in, const int* in_sizes, int n_in,
                              void* d_out, int out_size, void* d_ws, size_t ws_size,
                              hipStream_t stream) {
    const float* node   = (const float*)d_in[0];
    const float* adj    = (const float*)d_in[1];
    const float* W_edge = (const float*)d_in[2];
    const float* b_edge = (const float*)d_in[3];
    const float* W_add  = (const float*)d_in[4];
    const float* b_add  = (const float*)d_in[5];
    float* out = (float*)d_out;

    gconv_kernel<<<dim3(512), dim3(256), 0, stream>>>(
        node, adj, W_edge, b_edge, W_add, b_add, out);
}